// Round 15
// baseline (196.609 us; speedup 1.0000x reference)
//
#include <hip/hip_runtime.h>
#include <hip/hip_bf16.h>
#include <stdint.h>

typedef __attribute__((ext_vector_type(8))) short bf16x8;
typedef __attribute__((ext_vector_type(4))) float f32x4;

#define DEVFN static __device__ __forceinline__

typedef const __attribute__((address_space(1))) void* gas_ptr;
typedef __attribute__((address_space(3))) void* las_ptr;

// async global->LDS, 16B per lane; LDS dest = wave-uniform base + lane*16
DEVFN void async16(const void* g, void* l) {
  __builtin_amdgcn_global_load_lds((gas_ptr)g, (las_ptr)l, 16, 0, 0);
}

#define S_LEN 2048
#define NH    16
#define HDIM  64
#define KDIM  1024
#define NQKV  3072
#define MTOK  4096

// softmax scale 1/8 with log2(e) folded in (we use exp2 = native v_exp_f32)
#define QK_SCALE 0.1803368801111244f

// ---------------- fused prep: cast x + transpose both weights ----------------
__global__ __launch_bounds__(256) void prep_kernel(
    const float* __restrict__ x, const float* __restrict__ w_qkv,
    const float* __restrict__ w_out, __hip_bfloat16* __restrict__ xb,
    __hip_bfloat16* __restrict__ wqkt, __hip_bfloat16* __restrict__ wot) {
  __shared__ float T[64][65];
  const int j = blockIdx.x;
  const int tid = threadIdx.x;
  if (j < 2048) {
    const int i = (j * 256 + tid) * 8;
    float4 a = *(const float4*)(x + i);
    float4 b = *(const float4*)(x + i + 4);
    alignas(16) __hip_bfloat16 t[8] = {
        __float2bfloat16(a.x), __float2bfloat16(a.y),
        __float2bfloat16(a.z), __float2bfloat16(a.w),
        __float2bfloat16(b.x), __float2bfloat16(b.y),
        __float2bfloat16(b.z), __float2bfloat16(b.w)};
    *(uint4*)(xb + i) = *(const uint4*)t;
    return;
  }
  const float* in;
  __hip_bfloat16* out;
  int N, n0, k0;
  if (j < 2816) {
    const int j2 = j - 2048;  // 48 x 16
    in = w_qkv; out = wqkt; N = NQKV;
    n0 = (j2 % 48) * 64; k0 = (j2 / 48) * 64;
  } else {
    const int j3 = j - 2816;  // 16 x 16
    in = w_out; out = wot; N = KDIM;
    n0 = (j3 % 16) * 64; k0 = (j3 / 16) * 64;
  }
#pragma unroll
  for (int it = 0; it < 4; it++) {
    int r = it * 16 + (tid >> 4);
    int c = (tid & 15) * 4;
    float4 v = *(const float4*)&in[(size_t)(k0 + r) * N + n0 + c];
    T[r][c + 0] = v.x; T[r][c + 1] = v.y; T[r][c + 2] = v.z; T[r][c + 3] = v.w;
  }
  __syncthreads();
#pragma unroll
  for (int it = 0; it < 4; it++) {
    int rn = it * 16 + (tid >> 4);
    int ck = (tid & 15) * 4;
    alignas(8) __hip_bfloat16 t4[4];
#pragma unroll
    for (int jj = 0; jj < 4; jj++) t4[jj] = __float2bfloat16(T[ck + jj][rn]);
    *(ushort4*)&out[(size_t)(n0 + rn) * KDIM + k0 + ck] = *(const ushort4*)t4;
  }
}

// ---------------- QKV GEMM: (4096,1024)x(1024,3072)+bias, BK=64 ----------------
// __launch_bounds__(256,3): 3 blocks/CU (m114: wave-level MFMA/VALU overlap).
__global__ __launch_bounds__(256, 3) void qkv_gemm_kernel(
    const __hip_bfloat16* __restrict__ A,
    const __hip_bfloat16* __restrict__ Bt,
    const float* __restrict__ bias,
    __hip_bfloat16* __restrict__ qo,
    __hip_bfloat16* __restrict__ ko,
    __hip_bfloat16* __restrict__ vto) {
  __shared__ __hip_bfloat16 As[2][128 * 32];
  __shared__ __hip_bfloat16 Bs[2][128 * 32];
  __shared__ __hip_bfloat16 Tb[4][16 * 72];
  const int tid = threadIdx.x;
  const int wave = tid >> 6, lane = tid & 63;
  const int L = lane & 15, quad = lane >> 4;
  const int wm = wave >> 1, wn = wave & 1;
  const int m0 = blockIdx.y * 128, n0 = blockIdx.x * 128;

  f32x4 acc[4][4] = {};

  const int srow = tid >> 2;
  const int scol = (tid & 3) * 8;
  const __hip_bfloat16* ag = A + (size_t)(m0 + srow) * KDIM + scol;
  const __hip_bfloat16* bg = Bt + (size_t)(n0 + srow) * KDIM + scol;
  char* asd0 = (char*)&As[0][0] + wave * 1024;
  char* asd1 = (char*)&As[1][0] + wave * 1024;
  char* bsd0 = (char*)&Bs[0][0] + wave * 1024;
  char* bsd1 = (char*)&Bs[1][0] + wave * 1024;

  for (int kt = 0; kt < KDIM; kt += 64) {
    async16(ag + kt, asd0);
    async16(ag + kt + (size_t)64 * KDIM, asd0 + 4096);
    async16(ag + kt + 32, asd1);
    async16(ag + kt + 32 + (size_t)64 * KDIM, asd1 + 4096);
    async16(bg + kt, bsd0);
    async16(bg + kt + (size_t)64 * KDIM, bsd0 + 4096);
    async16(bg + kt + 32, bsd1);
    async16(bg + kt + 32 + (size_t)64 * KDIM, bsd1 + 4096);
    __syncthreads();
    bf16x8 af[4][2], bf[4][2];
#pragma unroll
    for (int r = 0; r < 4; r++)
#pragma unroll
      for (int kd = 0; kd < 2; kd++)
        af[r][kd] = *(const bf16x8*)&As[kd][(wm * 64 + r * 16 + L) * 32 + quad * 8];
#pragma unroll
    for (int c = 0; c < 4; c++)
#pragma unroll
      for (int kd = 0; kd < 2; kd++)
        bf[c][kd] = *(const bf16x8*)&Bs[kd][(wn * 64 + c * 16 + L) * 32 + quad * 8];
#pragma unroll
    for (int r = 0; r < 4; r++)
#pragma unroll
      for (int c = 0; c < 4; c++) {
        acc[r][c] = __builtin_amdgcn_mfma_f32_16x16x32_bf16(af[r][0], bf[c][0],
                                                            acc[r][c], 0, 0, 0);
        acc[r][c] = __builtin_amdgcn_mfma_f32_16x16x32_bf16(af[r][1], bf[c][1],
                                                            acc[r][c], 0, 0, 0);
      }
    __syncthreads();
  }

  const int mbase = m0 + wm * 64;
  const int nbase = n0 + wn * 64;
  const int h = nbase / 192;
  const int t = (nbase % 192) / 64;  // 0=Q 1=K 2=V
  const int b = mbase >> 11;
  const int s0 = mbase & 2047;
  __hip_bfloat16* Tw = &Tb[wave][0];
  float bv[4];
#pragma unroll
  for (int c = 0; c < 4; c++) bv[c] = bias[nbase + c * 16 + L];

  if (t == 2) {
#pragma unroll
    for (int c = 0; c < 4; c++) {
#pragma unroll
      for (int r = 0; r < 4; r++) {
        alignas(8) __hip_bfloat16 t4[4];
#pragma unroll
        for (int g = 0; g < 4; g++)
          t4[g] = __float2bfloat16(acc[r][c][g] + bv[c]);
        *(ushort4*)&Tw[L * 72 + r * 16 + quad * 4] = *(const ushort4*)t4;
      }
      __asm__ volatile("s_waitcnt lgkmcnt(0)" ::: "memory");
#pragma unroll
      for (int it = 0; it < 2; it++) {
        const int rr = it * 8 + (lane >> 3);
        const int cc = (lane & 7) * 8;
        uint4 u = *(const uint4*)&Tw[rr * 72 + cc];
        *(uint4*)&vto[((size_t)((b * NH + h) * HDIM + c * 16 + rr)) * S_LEN +
                      s0 + cc] = u;
      }
    }
  } else {
    __hip_bfloat16* dst = (t == 0) ? qo : ko;
    const float sc = (t == 0) ? QK_SCALE : 1.0f;
#pragma unroll
    for (int r = 0; r < 4; r++) {
#pragma unroll
      for (int c = 0; c < 4; c++)
#pragma unroll
        for (int g = 0; g < 4; g++)
          Tw[(quad * 4 + g) * 72 + c * 16 + L] =
              __float2bfloat16((acc[r][c][g] + bv[c]) * sc);
      __asm__ volatile("s_waitcnt lgkmcnt(0)" ::: "memory");
#pragma unroll
      for (int it = 0; it < 2; it++) {
        const int rr = it * 8 + (lane >> 3);
        const int cc = (lane & 7) * 8;
        uint4 u = *(const uint4*)&Tw[rr * 72 + cc];
        *(uint4*)&dst[((size_t)((b * NH + h) * S_LEN) + s0 + r * 16 + rr) *
                          HDIM + cc] = u;
      }
    }
  }
}

// ---------------- flash attention (causal), LDS-staged K/V ----------------
// R14 + equal-cost strip pairing. R14's occupancy (11%) showed the R12 pair
// (32-tile, 2-tile) leaves the big block running ~alone (1 wave/SIMD,
// latency-exposed chain) for most of the makespan. Now each block owns two
// NON-ADJACENT 64-row strips of its bh: strip 31-a (big) and strip a
// (small), one k-loop of 32-a tiles with the small strip masked off past
// tile a. Active-work per block = (32-a)+(a+1) = 33 for EVERY block ->
// equal wall time per block under any mapping, and both co-resident blocks
// stay alive to the end (2 waves/SIMD throughout). XCD locality unchanged
// (bh = j mod 8 -> FETCH ~12.3 MB). Ps split per (wave,r) to remove the
// r=0 P-read -> r=1 P-write LDS ordering.
__global__ __launch_bounds__(256, 2) void flash_attn_kernel(
    const __hip_bfloat16* __restrict__ q,
    const __hip_bfloat16* __restrict__ k,
    const __hip_bfloat16* __restrict__ vt,
    __hip_bfloat16* __restrict__ attn) {
  __shared__ __hip_bfloat16 Ks[2][64 * 72];  // [buf][row kk][g*8], pad 72
  __shared__ __hip_bfloat16 Vs[2][64 * 72];  // [buf][row d][g*8]
  __shared__ __hip_bfloat16 Ps[8][16 * 72];  // per (wave,r) P / O-transpose
  const int tid = threadIdx.x;
  const int wave = tid >> 6, lane = tid & 63;
  const int L = lane & 15, quad = lane >> 4;

  const int j = blockIdx.x;
  const int x = j & 7;           // XCD (round-robin dispatch) == bh & 7
  const int c = (j >> 3) & 31;   // CU slot within XCD
  const int rr = j >> 8;         // round
  const int bh = ((c & 3) << 3) + x;
  const int a = rr * 8 + (c >> 2);  // 0..15, once per bh
  // strips: r=0 -> rows (31-a)*64..+63 (big), r=1 -> rows a*64..+63 (small)

  const __hip_bfloat16* Qg = q + (size_t)bh * S_LEN * HDIM;
  const __hip_bfloat16* Kg = k + (size_t)bh * S_LEN * HDIM;
  const __hip_bfloat16* Vg = vt + (size_t)bh * HDIM * S_LEN;

  int wq[2];
  wq[0] = (31 - a) * 64 + wave * 16;
  wq[1] = a * 64 + wave * 16;

  // Q fragments (B-operand: n=q on L, k=d on quad*8+j), loaded once
  bf16x8 qf[2][2];
#pragma unroll
  for (int r = 0; r < 2; r++)
#pragma unroll
    for (int kd = 0; kd < 2; kd++)
      qf[r][kd] =
          *(const bf16x8*)&Qg[(size_t)(wq[r] + L) * HDIM + kd * 32 + quad * 8];

  float l_i[2] = {0.f, 0.f};
  f32x4 o[2][4] = {};  // O^T: o[r][dsb][g] = O^T[d=dsb*16+quad*4+g][q=L]

  // staging thread mapping: row32 = tid>>3 (0..31), g8 = tid&7 (16B chunk)
  const int row32 = tid >> 3;
  const int g8 = tid & 7;
  uint4 kreg[2], vreg[2];

  const int nkt = 32 - a;
  // prologue: stage tile 0 into buf 0
#pragma unroll
  for (int pp = 0; pp < 2; pp++) {
    kreg[pp] = *(const uint4*)&Kg[(size_t)(pp * 32 + row32) * HDIM + g8 * 8];
    vreg[pp] = *(const uint4*)&Vg[(size_t)(pp * 32 + row32) * S_LEN + g8 * 8];
  }
#pragma unroll
  for (int pp = 0; pp < 2; pp++) {
    *(uint4*)&Ks[0][(pp * 32 + row32) * 72 + g8 * 8] = kreg[pp];
    *(uint4*)&Vs[0][(pp * 32 + row32) * 72 + g8 * 8] = vreg[pp];
  }
  __syncthreads();

  for (int kt = 0; kt < nkt; kt++) {
    const int k0 = kt * 64;
    const int cur = kt & 1;
    // issue next tile's global loads first (drained at the ds_write below)
    if (kt + 1 < nkt) {
      const int k1 = k0 + 64;
#pragma unroll
      for (int pp = 0; pp < 2; pp++) {
        kreg[pp] =
            *(const uint4*)&Kg[(size_t)(k1 + pp * 32 + row32) * HDIM + g8 * 8];
        vreg[pp] =
            *(const uint4*)&Vg[(size_t)(pp * 32 + row32) * S_LEN + k1 + g8 * 8];
      }
    }

    // K frags (A-operand: m=kk on L, k=d on quad*8+j) from padded slab
    bf16x8 kfr[4][2], vfr[4][2];
#pragma unroll
    for (int ks = 0; ks < 4; ks++)
#pragma unroll
      for (int kd = 0; kd < 2; kd++)
        kfr[ks][kd] =
            *(const bf16x8*)&Ks[cur][(ks * 16 + L) * 72 + (kd * 4 + quad) * 8];
    // V^T frags (A-operand: m=d on L, k=kk on quad*8+j)
#pragma unroll
    for (int dsb = 0; dsb < 4; dsb++)
#pragma unroll
      for (int kf = 0; kf < 2; kf++)
        vfr[dsb][kf] =
            *(const bf16x8*)&Vs[cur][(dsb * 16 + L) * 72 + (kf * 4 + quad) * 8];

#pragma unroll
    for (int r = 0; r < 2; r++) {
      if (k0 > wq[r] + 15) continue;  // fully masked (wave-uniform)
      const int qrow = wq[r] + L;
      // S^T tile: st[ks] rows kk = k0+ks*16+quad*4+g, col q = wq[r]+L
      f32x4 st[4] = {};
#pragma unroll
      for (int ks = 0; ks < 4; ks++)
#pragma unroll
        for (int kd = 0; kd < 2; kd++)
          st[ks] = __builtin_amdgcn_mfma_f32_16x16x32_bf16(
              kfr[ks][kd], qf[r][kd], st[ks], 0, 0, 0);
      if (k0 + 63 > wq[r]) {  // diagonal tile: causal mask
#pragma unroll
        for (int ks = 0; ks < 4; ks++)
#pragma unroll
          for (int g = 0; g < 4; g++) {
            int kk = k0 + ks * 16 + quad * 4 + g;
            if (kk > qrow) st[ks][g] = -1e30f;
          }
      }
      // P = exp2(S) (no running max), accumulate per-lane partial l
      __hip_bfloat16* Pw = &Ps[wave * 2 + r][0];
      float rs = 0.f;
#pragma unroll
      for (int ks = 0; ks < 4; ks++) {
        f32x4 pv;
#pragma unroll
        for (int g = 0; g < 4; g++) {
          pv[g] = __builtin_amdgcn_exp2f(st[ks][g]);
          rs += pv[g];
        }
        alignas(8) __hip_bfloat16 t4[4];
#pragma unroll
        for (int g = 0; g < 4; g++) t4[g] = __float2bfloat16(pv[g]);
        // P[q][kk]: 4 consecutive kk for one q -> one b64 write
        *(ushort4*)&Pw[L * 72 + ks * 16 + quad * 4] = *(const ushort4*)t4;
      }
      l_i[r] += rs;
      __asm__ volatile("s_waitcnt lgkmcnt(0)" ::: "memory");  // wave-private
      bf16x8 pf[2];
#pragma unroll
      for (int kf = 0; kf < 2; kf++)
        pf[kf] = *(const bf16x8*)&Pw[L * 72 + kf * 32 + quad * 8];
#pragma unroll
      for (int dsb = 0; dsb < 4; dsb++)
#pragma unroll
        for (int kf = 0; kf < 2; kf++)
          o[r][dsb] = __builtin_amdgcn_mfma_f32_16x16x32_bf16(
              vfr[dsb][kf], pf[kf], o[r][dsb], 0, 0, 0);
    }

    // stage next tile into the other buffer, then one barrier
    if (kt + 1 < nkt) {
      const int nxt = cur ^ 1;
#pragma unroll
      for (int pp = 0; pp < 2; pp++) {
        *(uint4*)&Ks[nxt][(pp * 32 + row32) * 72 + g8 * 8] = kreg[pp];
        *(uint4*)&Vs[nxt][(pp * 32 + row32) * 72 + g8 * 8] = vreg[pp];
      }
      __syncthreads();
    }
  }

  const int b = bh >> 4, h = bh & 15;
#pragma unroll
  for (int r = 0; r < 2; r++) {
    __hip_bfloat16* Pw = &Ps[wave * 2 + r][0];
    float rs = l_i[r];  // reduce over quad axis (lane bits 4,5)
    rs += __shfl_xor(rs, 16, 64);
    rs += __shfl_xor(rs, 32, 64);
    const float linv = 1.0f / rs;
    // O^T -> wave-private LDS (same pattern as P writes)
#pragma unroll
    for (int dsb = 0; dsb < 4; dsb++) {
      alignas(8) __hip_bfloat16 t4[4];
#pragma unroll
      for (int g = 0; g < 4; g++)
        t4[g] = __float2bfloat16(o[r][dsb][g] * linv);
      *(ushort4*)&Pw[L * 72 + dsb * 16 + quad * 4] = *(const ushort4*)t4;
    }
    __asm__ volatile("s_waitcnt lgkmcnt(0)" ::: "memory");
    // coalesced store: 8 lanes cover one full 128-B row
#pragma unroll
    for (int it = 0; it < 2; it++) {
      const int row = it * 8 + (lane >> 3);
      const int col = (lane & 7) * 8;
      uint4 u = *(const uint4*)&Pw[row * 72 + col];
      *(uint4*)&attn[((size_t)(b * S_LEN + wq[r] + row)) * 1024 + h * 64 + col] = u;
    }
  }
}

// ---------------- out GEMM: (4096,1024)x(1024,1024)+bias -> fp32, BK=64 --------
__global__ __launch_bounds__(256, 2) void out_gemm_kernel(
    const __hip_bfloat16* __restrict__ A,
    const __hip_bfloat16* __restrict__ Bt,
    const float* __restrict__ bias,
    float* __restrict__ out) {
  __shared__ __hip_bfloat16 As[2][128 * 32];
  __shared__ __hip_bfloat16 Bs[2][64 * 32];
  __shared__ float Os[4][16 * 36];
  const int tid = threadIdx.x;
  const int wave = tid >> 6, lane = tid & 63;
  const int L = lane & 15, quad = lane >> 4;
  const int wm = wave >> 1, wn = wave & 1;
  const int m0 = blockIdx.y * 128, n0 = blockIdx.x * 64;

  f32x4 acc[4][2] = {};

  const int srow = tid >> 2;
  const int scol = (tid & 3) * 8;
  const __hip_bfloat16* ag = A + (size_t)(m0 + srow) * KDIM + scol;
  const __hip_bfloat16* bg = Bt + (size_t)(n0 + srow) * KDIM + scol;
  char* asd0 = (char*)&As[0][0] + wave * 1024;
  char* asd1 = (char*)&As[1][0] + wave * 1024;
  char* bsd0 = (char*)&Bs[0][0] + wave * 1024;
  char* bsd1 = (char*)&Bs[1][0] + wave * 1024;

  for (int kt = 0; kt < KDIM; kt += 64) {
    async16(ag + kt, asd0);
    async16(ag + kt + (size_t)64 * KDIM, asd0 + 4096);
    async16(ag + kt + 32, asd1);
    async16(ag + kt + 32 + (size_t)64 * KDIM, asd1 + 4096);
    async16(bg + kt, bsd0);
    async16(bg + kt + 32, bsd1);
    __syncthreads();
    bf16x8 af[4][2], bf[2][2];
#pragma unroll
    for (int r = 0; r < 4; r++)
#pragma unroll
      for (int kd = 0; kd < 2; kd++)
        af[r][kd] = *(const bf16x8*)&As[kd][(wm * 64 + r * 16 + L) * 32 + quad * 8];
#pragma unroll
    for (int c = 0; c < 2; c++)
#pragma unroll
      for (int kd = 0; kd < 2; kd++)
        bf[c][kd] = *(const bf16x8*)&Bs[kd][(wn * 32 + c * 16 + L) * 32 + quad * 8];
#pragma unroll
    for (int r = 0; r < 4; r++)
#pragma unroll
      for (int c = 0; c < 2; c++) {
        acc[r][c] = __builtin_amdgcn_mfma_f32_16x16x32_bf16(af[r][0], bf[c][0],
                                                            acc[r][c], 0, 0, 0);
        acc[r][c] = __builtin_amdgcn_mfma_f32_16x16x32_bf16(af[r][1], bf[c][1],
                                                            acc[r][c], 0, 0, 0);
      }
    __syncthreads();
  }

  float bv[2];
#pragma unroll
  for (int c = 0; c < 2; c++) bv[c] = bias[n0 + wn * 32 + c * 16 + L];
#pragma unroll
  for (int r = 0; r < 4; r++) {
#pragma unroll
    for (int c = 0; c < 2; c++)
#pragma unroll
      for (int g = 0; g < 4; g++)
        Os[wave][(quad * 4 + g) * 36 + c * 16 + L] = acc[r][c][g] + bv[c];
    __asm__ volatile("s_waitcnt lgkmcnt(0)" ::: "memory");  // wave-private
#pragma unroll
    for (int it = 0; it < 2; it++) {
      const int row = it * 8 + (lane >> 3);
      const int ncol = (lane & 7) * 4;
      float4 u = *(const float4*)&Os[wave][row * 36 + ncol];
      *(float4*)&out[(size_t)(m0 + wm * 64 + r * 16 + row) * 1024 + n0 +
                     wn * 32 + ncol] = u;
    }
  }
}

extern "C" void kernel_launch(void* const* d_in, const int* in_sizes, int n_in,
                              void* d_out, int out_size, void* d_ws, size_t ws_size,
                              hipStream_t stream) {
  const float* x     = (const float*)d_in[0];
  const float* w_qkv = (const float*)d_in[1];
  const float* b_qkv = (const float*)d_in[2];
  const float* w_out = (const float*)d_in[3];
  const float* b_out = (const float*)d_in[4];
  float* out = (float*)d_out;

  __hip_bfloat16* ws = (__hip_bfloat16*)d_ws;
  __hip_bfloat16* xb   = ws;                          // 4096x1024
  __hip_bfloat16* wqkt = xb   + (size_t)4194304;      // 3072x1024 (w_qkv^T)
  __hip_bfloat16* wot  = wqkt + (size_t)3145728;      // 1024x1024 (w_out^T)
  __hip_bfloat16* qb   = wot  + (size_t)1048576;      // [2][16][2048][64]
  __hip_bfloat16* kb   = qb   + (size_t)4194304;
  __hip_bfloat16* vtb  = kb   + (size_t)4194304;      // [2][16][64][2048]
  __hip_bfloat16* attn = vtb  + (size_t)4194304;      // [2][2048][1024]

  prep_kernel<<<3072, 256, 0, stream>>>(x, w_qkv, w_out, xb, wqkt, wot);
  qkv_gemm_kernel<<<dim3(NQKV / 128, MTOK / 128), 256, 0, stream>>>(
      xb, wqkt, b_qkv, qb, kb, vtb);
  flash_attn_kernel<<<512, 256, 0, stream>>>(qb, kb, vtb, attn);
  out_gemm_kernel<<<dim3(KDIM / 64, MTOK / 128), 256, 0, stream>>>(
      attn, wot, b_out, out);
}

// Round 16
// 163.454 us; speedup vs baseline: 1.2028x; 1.2028x over previous
//
#include <hip/hip_runtime.h>
#include <hip/hip_bf16.h>
#include <stdint.h>

typedef __attribute__((ext_vector_type(8))) short bf16x8;
typedef __attribute__((ext_vector_type(4))) float f32x4;

#define DEVFN static __device__ __forceinline__

typedef const __attribute__((address_space(1))) void* gas_ptr;
typedef __attribute__((address_space(3))) void* las_ptr;

// async global->LDS, 16B per lane; LDS dest = wave-uniform base + lane*16
DEVFN void async16(const void* g, void* l) {
  __builtin_amdgcn_global_load_lds((gas_ptr)g, (las_ptr)l, 16, 0, 0);
}

#define S_LEN 2048
#define NH    16
#define HDIM  64
#define KDIM  1024
#define NQKV  3072
#define MTOK  4096

// softmax scale 1/8 with log2(e) folded in (we use exp2 = native v_exp_f32)
#define QK_SCALE 0.1803368801111244f

// ---------------- fused prep: cast x + transpose both weights ----------------
__global__ __launch_bounds__(256) void prep_kernel(
    const float* __restrict__ x, const float* __restrict__ w_qkv,
    const float* __restrict__ w_out, __hip_bfloat16* __restrict__ xb,
    __hip_bfloat16* __restrict__ wqkt, __hip_bfloat16* __restrict__ wot) {
  __shared__ float T[64][65];
  const int j = blockIdx.x;
  const int tid = threadIdx.x;
  if (j < 2048) {
    const int i = (j * 256 + tid) * 8;
    float4 a = *(const float4*)(x + i);
    float4 b = *(const float4*)(x + i + 4);
    alignas(16) __hip_bfloat16 t[8] = {
        __float2bfloat16(a.x), __float2bfloat16(a.y),
        __float2bfloat16(a.z), __float2bfloat16(a.w),
        __float2bfloat16(b.x), __float2bfloat16(b.y),
        __float2bfloat16(b.z), __float2bfloat16(b.w)};
    *(uint4*)(xb + i) = *(const uint4*)t;
    return;
  }
  const float* in;
  __hip_bfloat16* out;
  int N, n0, k0;
  if (j < 2816) {
    const int j2 = j - 2048;  // 48 x 16
    in = w_qkv; out = wqkt; N = NQKV;
    n0 = (j2 % 48) * 64; k0 = (j2 / 48) * 64;
  } else {
    const int j3 = j - 2816;  // 16 x 16
    in = w_out; out = wot; N = KDIM;
    n0 = (j3 % 16) * 64; k0 = (j3 / 16) * 64;
  }
#pragma unroll
  for (int it = 0; it < 4; it++) {
    int r = it * 16 + (tid >> 4);
    int c = (tid & 15) * 4;
    float4 v = *(const float4*)&in[(size_t)(k0 + r) * N + n0 + c];
    T[r][c + 0] = v.x; T[r][c + 1] = v.y; T[r][c + 2] = v.z; T[r][c + 3] = v.w;
  }
  __syncthreads();
#pragma unroll
  for (int it = 0; it < 4; it++) {
    int rn = it * 16 + (tid >> 4);
    int ck = (tid & 15) * 4;
    alignas(8) __hip_bfloat16 t4[4];
#pragma unroll
    for (int jj = 0; jj < 4; jj++) t4[jj] = __float2bfloat16(T[ck + jj][rn]);
    *(ushort4*)&out[(size_t)(n0 + rn) * KDIM + k0 + ck] = *(const ushort4*)t4;
  }
}

// ---------------- QKV GEMM: (4096,1024)x(1024,3072)+bias, BK=64 ----------------
// __launch_bounds__(256,3): 3 blocks/CU (m114: wave-level MFMA/VALU overlap).
__global__ __launch_bounds__(256, 3) void qkv_gemm_kernel(
    const __hip_bfloat16* __restrict__ A,
    const __hip_bfloat16* __restrict__ Bt,
    const float* __restrict__ bias,
    __hip_bfloat16* __restrict__ qo,
    __hip_bfloat16* __restrict__ ko,
    __hip_bfloat16* __restrict__ vto) {
  __shared__ __hip_bfloat16 As[2][128 * 32];
  __shared__ __hip_bfloat16 Bs[2][128 * 32];
  __shared__ __hip_bfloat16 Tb[4][16 * 72];
  const int tid = threadIdx.x;
  const int wave = tid >> 6, lane = tid & 63;
  const int L = lane & 15, quad = lane >> 4;
  const int wm = wave >> 1, wn = wave & 1;
  const int m0 = blockIdx.y * 128, n0 = blockIdx.x * 128;

  f32x4 acc[4][4] = {};

  const int srow = tid >> 2;
  const int scol = (tid & 3) * 8;
  const __hip_bfloat16* ag = A + (size_t)(m0 + srow) * KDIM + scol;
  const __hip_bfloat16* bg = Bt + (size_t)(n0 + srow) * KDIM + scol;
  char* asd0 = (char*)&As[0][0] + wave * 1024;
  char* asd1 = (char*)&As[1][0] + wave * 1024;
  char* bsd0 = (char*)&Bs[0][0] + wave * 1024;
  char* bsd1 = (char*)&Bs[1][0] + wave * 1024;

  for (int kt = 0; kt < KDIM; kt += 64) {
    async16(ag + kt, asd0);
    async16(ag + kt + (size_t)64 * KDIM, asd0 + 4096);
    async16(ag + kt + 32, asd1);
    async16(ag + kt + 32 + (size_t)64 * KDIM, asd1 + 4096);
    async16(bg + kt, bsd0);
    async16(bg + kt + (size_t)64 * KDIM, bsd0 + 4096);
    async16(bg + kt + 32, bsd1);
    async16(bg + kt + 32 + (size_t)64 * KDIM, bsd1 + 4096);
    __syncthreads();
    bf16x8 af[4][2], bf[4][2];
#pragma unroll
    for (int r = 0; r < 4; r++)
#pragma unroll
      for (int kd = 0; kd < 2; kd++)
        af[r][kd] = *(const bf16x8*)&As[kd][(wm * 64 + r * 16 + L) * 32 + quad * 8];
#pragma unroll
    for (int c = 0; c < 4; c++)
#pragma unroll
      for (int kd = 0; kd < 2; kd++)
        bf[c][kd] = *(const bf16x8*)&Bs[kd][(wn * 64 + c * 16 + L) * 32 + quad * 8];
#pragma unroll
    for (int r = 0; r < 4; r++)
#pragma unroll
      for (int c = 0; c < 4; c++) {
        acc[r][c] = __builtin_amdgcn_mfma_f32_16x16x32_bf16(af[r][0], bf[c][0],
                                                            acc[r][c], 0, 0, 0);
        acc[r][c] = __builtin_amdgcn_mfma_f32_16x16x32_bf16(af[r][1], bf[c][1],
                                                            acc[r][c], 0, 0, 0);
      }
    __syncthreads();
  }

  const int mbase = m0 + wm * 64;
  const int nbase = n0 + wn * 64;
  const int h = nbase / 192;
  const int t = (nbase % 192) / 64;  // 0=Q 1=K 2=V
  const int b = mbase >> 11;
  const int s0 = mbase & 2047;
  __hip_bfloat16* Tw = &Tb[wave][0];
  float bv[4];
#pragma unroll
  for (int c = 0; c < 4; c++) bv[c] = bias[nbase + c * 16 + L];

  if (t == 2) {
#pragma unroll
    for (int c = 0; c < 4; c++) {
#pragma unroll
      for (int r = 0; r < 4; r++) {
        alignas(8) __hip_bfloat16 t4[4];
#pragma unroll
        for (int g = 0; g < 4; g++)
          t4[g] = __float2bfloat16(acc[r][c][g] + bv[c]);
        *(ushort4*)&Tw[L * 72 + r * 16 + quad * 4] = *(const ushort4*)t4;
      }
      __asm__ volatile("s_waitcnt lgkmcnt(0)" ::: "memory");
#pragma unroll
      for (int it = 0; it < 2; it++) {
        const int rr = it * 8 + (lane >> 3);
        const int cc = (lane & 7) * 8;
        uint4 u = *(const uint4*)&Tw[rr * 72 + cc];
        *(uint4*)&vto[((size_t)((b * NH + h) * HDIM + c * 16 + rr)) * S_LEN +
                      s0 + cc] = u;
      }
    }
  } else {
    __hip_bfloat16* dst = (t == 0) ? qo : ko;
    const float sc = (t == 0) ? QK_SCALE : 1.0f;
#pragma unroll
    for (int r = 0; r < 4; r++) {
#pragma unroll
      for (int c = 0; c < 4; c++)
#pragma unroll
        for (int g = 0; g < 4; g++)
          Tw[(quad * 4 + g) * 72 + c * 16 + L] =
              __float2bfloat16((acc[r][c][g] + bv[c]) * sc);
      __asm__ volatile("s_waitcnt lgkmcnt(0)" ::: "memory");
#pragma unroll
      for (int it = 0; it < 2; it++) {
        const int rr = it * 8 + (lane >> 3);
        const int cc = (lane & 7) * 8;
        uint4 u = *(const uint4*)&Tw[rr * 72 + cc];
        *(uint4*)&dst[((size_t)((b * NH + h) * S_LEN) + s0 + r * 16 + rr) *
                          HDIM + cc] = u;
      }
    }
  }
}

// ---------------- flash attention (causal), LDS-staged K/V, 8 waves ----------
// R14 structure + 512 threads: 8 waves each own ONE 16-row q-frag of the
// 128-row block. R15 taught: the binding constraint is serial chain length
// x exposed latency on the makespan CU (runs ~1 wave/SIMD in R14's tail).
// R10's 8-wave idea was right but died on L1/HBM frag duplication (FETCH
// 2x); since R13 frags come from SHARED LDS, so wave count no longer
// multiplies traffic: staging = 1 uint4/thread/tile (same bytes as R14),
// and the makespan tail now runs 2 waves/SIMD. kfr/vfr never co-live
// (vfr loaded after P write) -> ~100 VGPR, fits (512,4); LDS 55 KB ->
// 2 blocks/CU. Decode = R12/R14 (XCD-local bh=j&7 via pure-bh mapping,
// big+small per-CU pairing, FETCH 12.3 MB).
__global__ __launch_bounds__(512, 4) void flash_attn_kernel(
    const __hip_bfloat16* __restrict__ q,
    const __hip_bfloat16* __restrict__ k,
    const __hip_bfloat16* __restrict__ vt,
    __hip_bfloat16* __restrict__ attn) {
  __shared__ __hip_bfloat16 Ks[2][64 * 72];  // [buf][row kk][g*8], pad 72
  __shared__ __hip_bfloat16 Vs[2][64 * 72];  // [buf][row d][g*8]
  __shared__ __hip_bfloat16 Ps[8][16 * 72];  // wave-private P / O-transpose
  const int tid = threadIdx.x;
  const int wave = tid >> 6, lane = tid & 63;
  const int L = lane & 15, quad = lane >> 4;

  const int j = blockIdx.x;
  const int x = j & 7;           // XCD (round-robin dispatch)
  const int c = (j >> 3) & 31;   // CU slot within XCD
  const int rr = j >> 8;         // round 0 = big, 1 = small
  const int bh = ((c & 3) << 3) + x;
  const int p = c >> 2;          // 0..7
  const int qi = rr ? p : (15 - p);
  const int qb = qi * 128;

  const __hip_bfloat16* Qg = q + (size_t)bh * S_LEN * HDIM;
  const __hip_bfloat16* Kg = k + (size_t)bh * S_LEN * HDIM;
  const __hip_bfloat16* Vg = vt + (size_t)bh * HDIM * S_LEN;

  const int wq = qb + wave * 16;
  const int qrow = wq + L;

  // Q fragment (B-operand: n=q on L, k=d on quad*8+j), loaded once
  bf16x8 qf[2];
#pragma unroll
  for (int kd = 0; kd < 2; kd++)
    qf[kd] = *(const bf16x8*)&Qg[(size_t)qrow * HDIM + kd * 32 + quad * 8];

  float l_i = 0.f;
  f32x4 o[4] = {};  // O^T: o[dsb][g] = O^T[d=dsb*16+quad*4+g][q=L]

  // staging thread mapping: row64 = tid>>3 (0..63), g8 = tid&7 (16B chunk)
  const int row64 = tid >> 3;
  const int g8 = tid & 7;
  uint4 kreg, vreg;

  const int nkt = 2 * (qi + 1);
  // prologue: stage tile 0 into buf 0
  kreg = *(const uint4*)&Kg[(size_t)row64 * HDIM + g8 * 8];
  vreg = *(const uint4*)&Vg[(size_t)row64 * S_LEN + g8 * 8];
  *(uint4*)&Ks[0][row64 * 72 + g8 * 8] = kreg;
  *(uint4*)&Vs[0][row64 * 72 + g8 * 8] = vreg;
  __syncthreads();

  for (int kt = 0; kt < nkt; kt++) {
    const int k0 = kt * 64;
    const int cur = kt & 1;
    // issue next tile's global loads first (drained at the ds_write below)
    if (kt + 1 < nkt) {
      const int k1 = k0 + 64;
      kreg = *(const uint4*)&Kg[(size_t)(k1 + row64) * HDIM + g8 * 8];
      vreg = *(const uint4*)&Vg[(size_t)row64 * S_LEN + k1 + g8 * 8];
    }

    if (k0 <= wq + 15) {  // wave-uniform: at least one unmasked column
      // K frags (A-operand: m=kk on L, k=d on quad*8+j) from padded slab
      bf16x8 kfr[4][2];
#pragma unroll
      for (int ks = 0; ks < 4; ks++)
#pragma unroll
        for (int kd = 0; kd < 2; kd++)
          kfr[ks][kd] =
              *(const bf16x8*)&Ks[cur][(ks * 16 + L) * 72 + (kd * 4 + quad) * 8];
      // S^T tile: st[ks] rows kk = k0+ks*16+quad*4+g, col q = wq+L
      f32x4 st[4] = {};
#pragma unroll
      for (int ks = 0; ks < 4; ks++)
#pragma unroll
        for (int kd = 0; kd < 2; kd++)
          st[ks] = __builtin_amdgcn_mfma_f32_16x16x32_bf16(
              kfr[ks][kd], qf[kd], st[ks], 0, 0, 0);
      if (k0 + 63 > wq) {  // diagonal tile: causal mask
#pragma unroll
        for (int ks = 0; ks < 4; ks++)
#pragma unroll
          for (int g = 0; g < 4; g++) {
            int kk = k0 + ks * 16 + quad * 4 + g;
            if (kk > qrow) st[ks][g] = -1e30f;
          }
      }
      // P = exp2(S) (no running max), accumulate per-lane partial l
      __hip_bfloat16* Pw = &Ps[wave][0];
      float rs = 0.f;
#pragma unroll
      for (int ks = 0; ks < 4; ks++) {
        f32x4 pv;
#pragma unroll
        for (int g = 0; g < 4; g++) {
          pv[g] = __builtin_amdgcn_exp2f(st[ks][g]);
          rs += pv[g];
        }
        alignas(8) __hip_bfloat16 t4[4];
#pragma unroll
        for (int g = 0; g < 4; g++) t4[g] = __float2bfloat16(pv[g]);
        // P[q][kk]: 4 consecutive kk for one q -> one b64 write
        *(ushort4*)&Pw[L * 72 + ks * 16 + quad * 4] = *(const ushort4*)t4;
      }
      l_i += rs;
      __asm__ volatile("s_waitcnt lgkmcnt(0)" ::: "memory");  // wave-private
      bf16x8 pf[2];
#pragma unroll
      for (int kf = 0; kf < 2; kf++)
        pf[kf] = *(const bf16x8*)&Pw[L * 72 + kf * 32 + quad * 8];
      // V^T frags (A-operand: m=d on L, k=kk on quad*8+j), loaded after P
      // so kfr/vfr never co-live (VGPR cap 128 at 4 waves/SIMD)
#pragma unroll
      for (int dsb = 0; dsb < 4; dsb++) {
#pragma unroll
        for (int kf = 0; kf < 2; kf++) {
          bf16x8 vf =
              *(const bf16x8*)&Vs[cur][(dsb * 16 + L) * 72 + (kf * 4 + quad) * 8];
          o[dsb] = __builtin_amdgcn_mfma_f32_16x16x32_bf16(vf, pf[kf], o[dsb],
                                                           0, 0, 0);
        }
      }
    }

    // stage next tile into the other buffer, then one barrier
    if (kt + 1 < nkt) {
      const int nxt = cur ^ 1;
      *(uint4*)&Ks[nxt][row64 * 72 + g8 * 8] = kreg;
      *(uint4*)&Vs[nxt][row64 * 72 + g8 * 8] = vreg;
      __syncthreads();
    }
  }

  const int b = bh >> 4, h = bh & 15;
  __hip_bfloat16* Pw = &Ps[wave][0];
  float rs = l_i;  // reduce over quad axis (lane bits 4,5)
  rs += __shfl_xor(rs, 16, 64);
  rs += __shfl_xor(rs, 32, 64);
  const float linv = 1.0f / rs;
  // O^T -> wave-private LDS (same pattern as P writes)
#pragma unroll
  for (int dsb = 0; dsb < 4; dsb++) {
    alignas(8) __hip_bfloat16 t4[4];
#pragma unroll
    for (int g = 0; g < 4; g++) t4[g] = __float2bfloat16(o[dsb][g] * linv);
    *(ushort4*)&Pw[L * 72 + dsb * 16 + quad * 4] = *(const ushort4*)t4;
  }
  __asm__ volatile("s_waitcnt lgkmcnt(0)" ::: "memory");
  // coalesced store: 8 lanes cover one full 128-B row
#pragma unroll
  for (int it = 0; it < 2; it++) {
    const int row = it * 8 + (lane >> 3);
    const int col = (lane & 7) * 8;
    uint4 u = *(const uint4*)&Pw[row * 72 + col];
    *(uint4*)&attn[((size_t)(b * S_LEN + wq + row)) * 1024 + h * 64 + col] = u;
  }
}

// ---------------- out GEMM: (4096,1024)x(1024,1024)+bias -> fp32, BK=64 --------
__global__ __launch_bounds__(256, 2) void out_gemm_kernel(
    const __hip_bfloat16* __restrict__ A,
    const __hip_bfloat16* __restrict__ Bt,
    const float* __restrict__ bias,
    float* __restrict__ out) {
  __shared__ __hip_bfloat16 As[2][128 * 32];
  __shared__ __hip_bfloat16 Bs[2][64 * 32];
  __shared__ float Os[4][16 * 36];
  const int tid = threadIdx.x;
  const int wave = tid >> 6, lane = tid & 63;
  const int L = lane & 15, quad = lane >> 4;
  const int wm = wave >> 1, wn = wave & 1;
  const int m0 = blockIdx.y * 128, n0 = blockIdx.x * 64;

  f32x4 acc[4][2] = {};

  const int srow = tid >> 2;
  const int scol = (tid & 3) * 8;
  const __hip_bfloat16* ag = A + (size_t)(m0 + srow) * KDIM + scol;
  const __hip_bfloat16* bg = Bt + (size_t)(n0 + srow) * KDIM + scol;
  char* asd0 = (char*)&As[0][0] + wave * 1024;
  char* asd1 = (char*)&As[1][0] + wave * 1024;
  char* bsd0 = (char*)&Bs[0][0] + wave * 1024;
  char* bsd1 = (char*)&Bs[1][0] + wave * 1024;

  for (int kt = 0; kt < KDIM; kt += 64) {
    async16(ag + kt, asd0);
    async16(ag + kt + (size_t)64 * KDIM, asd0 + 4096);
    async16(ag + kt + 32, asd1);
    async16(ag + kt + 32 + (size_t)64 * KDIM, asd1 + 4096);
    async16(bg + kt, bsd0);
    async16(bg + kt + 32, bsd1);
    __syncthreads();
    bf16x8 af[4][2], bf[2][2];
#pragma unroll
    for (int r = 0; r < 4; r++)
#pragma unroll
      for (int kd = 0; kd < 2; kd++)
        af[r][kd] = *(const bf16x8*)&As[kd][(wm * 64 + r * 16 + L) * 32 + quad * 8];
#pragma unroll
    for (int c = 0; c < 2; c++)
#pragma unroll
      for (int kd = 0; kd < 2; kd++)
        bf[c][kd] = *(const bf16x8*)&Bs[kd][(wn * 32 + c * 16 + L) * 32 + quad * 8];
#pragma unroll
    for (int r = 0; r < 4; r++)
#pragma unroll
      for (int c = 0; c < 2; c++) {
        acc[r][c] = __builtin_amdgcn_mfma_f32_16x16x32_bf16(af[r][0], bf[c][0],
                                                            acc[r][c], 0, 0, 0);
        acc[r][c] = __builtin_amdgcn_mfma_f32_16x16x32_bf16(af[r][1], bf[c][1],
                                                            acc[r][c], 0, 0, 0);
      }
    __syncthreads();
  }

  float bv[2];
#pragma unroll
  for (int c = 0; c < 2; c++) bv[c] = bias[n0 + wn * 32 + c * 16 + L];
#pragma unroll
  for (int r = 0; r < 4; r++) {
#pragma unroll
    for (int c = 0; c < 2; c++)
#pragma unroll
      for (int g = 0; g < 4; g++)
        Os[wave][(quad * 4 + g) * 36 + c * 16 + L] = acc[r][c][g] + bv[c];
    __asm__ volatile("s_waitcnt lgkmcnt(0)" ::: "memory");  // wave-private
#pragma unroll
    for (int it = 0; it < 2; it++) {
      const int row = it * 8 + (lane >> 3);
      const int ncol = (lane & 7) * 4;
      float4 u = *(const float4*)&Os[wave][row * 36 + ncol];
      *(float4*)&out[(size_t)(m0 + wm * 64 + r * 16 + row) * 1024 + n0 +
                     wn * 32 + ncol] = u;
    }
  }
}

extern "C" void kernel_launch(void* const* d_in, const int* in_sizes, int n_in,
                              void* d_out, int out_size, void* d_ws, size_t ws_size,
                              hipStream_t stream) {
  const float* x     = (const float*)d_in[0];
  const float* w_qkv = (const float*)d_in[1];
  const float* b_qkv = (const float*)d_in[2];
  const float* w_out = (const float*)d_in[3];
  const float* b_out = (const float*)d_in[4];
  float* out = (float*)d_out;

  __hip_bfloat16* ws = (__hip_bfloat16*)d_ws;
  __hip_bfloat16* xb   = ws;                          // 4096x1024
  __hip_bfloat16* wqkt = xb   + (size_t)4194304;      // 3072x1024 (w_qkv^T)
  __hip_bfloat16* wot  = wqkt + (size_t)3145728;      // 1024x1024 (w_out^T)
  __hip_bfloat16* qb   = wot  + (size_t)1048576;      // [2][16][2048][64]
  __hip_bfloat16* kb   = qb   + (size_t)4194304;
  __hip_bfloat16* vtb  = kb   + (size_t)4194304;      // [2][16][64][2048]
  __hip_bfloat16* attn = vtb  + (size_t)4194304;      // [2][2048][1024]

  prep_kernel<<<3072, 256, 0, stream>>>(x, w_qkv, w_out, xb, wqkt, wot);
  qkv_gemm_kernel<<<dim3(NQKV / 128, MTOK / 128), 256, 0, stream>>>(
      xb, wqkt, b_qkv, qb, kb, vtb);
  flash_attn_kernel<<<512, 512, 0, stream>>>(qb, kb, vtb, attn);
  out_gemm_kernel<<<dim3(KDIM / 64, MTOK / 128), 256, 0, stream>>>(
      attn, wot, b_out, out);
}